// Round 1
// baseline (173.409 us; speedup 1.0000x reference)
//
#include <hip/hip_runtime.h>
#include <math.h>

// Paged-attention GQA decode, fp32, flash-decode split-K.
// q:(1,32,128) k,v:(1,8,128) k_cache,v_cache:(16384,8,128)
// block_table:(512,) slot_mapping:(1,) -> out:(1,32,128)

#define NUM_HEADS    32
#define NUM_KV_HEADS 8
#define GQA          4      // query heads per kv head
#define HEAD_DIM     128
#define ATTN_SCALE   0.08838834764831845f
#define CTX          8192
#define BLK          16     // paged block size
#define SPLITS       64
#define CHUNK        (CTX / SPLITS)      // 128 positions per block
#define POS_PER_WAVE (CHUNK / 4)         // 32 per wave
#define ITERS        (POS_PER_WAVE / 2)  // 16 (2 positions/iter, one per half-wave)

// ---------------- kernel 1: per-split partial attention ----------------
__global__ __launch_bounds__(256) void attn_partial(
    const float* __restrict__ q,
    const float* __restrict__ knew,
    const float* __restrict__ vnew,
    const float* __restrict__ kc,
    const float* __restrict__ vc,
    const int*   __restrict__ bt,
    float*       __restrict__ o_part,   // [32][SPLITS][128]
    float2*      __restrict__ ml_part)  // [32][SPLITS]
{
    const int split = blockIdx.x;
    const int kvh   = blockIdx.y;
    const int tid   = threadIdx.x;
    const int wave  = tid >> 6;
    const int lane  = tid & 63;
    const int half  = lane >> 5;   // which half-wave
    const int l     = lane & 31;   // lane within half

    // Preload Q fragments: 4 heads x 4 contiguous elems at d = l*4
    float4 qf[GQA];
#pragma unroll
    for (int h = 0; h < GQA; ++h)
        qf[h] = *(const float4*)(q + (kvh * GQA + h) * HEAD_DIM + l * 4);

    float  m[GQA], lsum[GQA];
    float4 o[GQA];
#pragma unroll
    for (int h = 0; h < GQA; ++h) {
        m[h] = -INFINITY; lsum[h] = 0.f;
        o[h] = make_float4(0.f, 0.f, 0.f, 0.f);
    }

    const int base = split * CHUNK + wave * POS_PER_WAVE;

    for (int it = 0; it < ITERS; ++it) {
        const int pos  = base + it * 2 + half;
        const int slot = bt[pos >> 4] * BLK + (pos & 15);

        const float* kptr;
        const float* vptr;
        if (pos == CTX - 1) {          // new token: read fresh k/v, skip cache
            kptr = knew + kvh * HEAD_DIM;
            vptr = vnew + kvh * HEAD_DIM;
        } else {
            const size_t row = ((size_t)slot * NUM_KV_HEADS + kvh) * HEAD_DIM;
            kptr = kc + row;
            vptr = vc + row;
        }
        const float4 kf = *(const float4*)(kptr + l * 4);
        const float4 vf = *(const float4*)(vptr + l * 4);

        float s[GQA];
#pragma unroll
        for (int h = 0; h < GQA; ++h)
            s[h] = qf[h].x * kf.x + qf[h].y * kf.y + qf[h].z * kf.z + qf[h].w * kf.w;

        // butterfly reduce across the 32-lane half (xor < 32 stays in-half)
#pragma unroll
        for (int off = 16; off >= 1; off >>= 1) {
#pragma unroll
            for (int h = 0; h < GQA; ++h)
                s[h] += __shfl_xor(s[h], off, 64);
        }

#pragma unroll
        for (int h = 0; h < GQA; ++h) {
            const float sc    = s[h] * ATTN_SCALE;
            const float mn    = fmaxf(m[h], sc);
            const float alpha = __expf(m[h] - mn);
            const float p     = __expf(sc - mn);
            m[h] = mn;
            lsum[h] = lsum[h] * alpha + p;
            o[h].x = o[h].x * alpha + p * vf.x;
            o[h].y = o[h].y * alpha + p * vf.y;
            o[h].z = o[h].z * alpha + p * vf.z;
            o[h].w = o[h].w * alpha + p * vf.w;
        }
    }

    // ---- combine the 8 half-waves of this block via LDS ----
    __shared__ float lds_o[8][GQA][HEAD_DIM];
    __shared__ float lds_m[8][GQA];
    __shared__ float lds_l[8][GQA];

    const int halfid = tid >> 5;   // 0..7
#pragma unroll
    for (int h = 0; h < GQA; ++h) {
        *(float4*)&lds_o[halfid][h][l * 4] = o[h];
        if (l == 0) { lds_m[halfid][h] = m[h]; lds_l[halfid][h] = lsum[h]; }
    }
    __syncthreads();

    if (tid < HEAD_DIM) {
        const int d = tid;
#pragma unroll
        for (int h = 0; h < GQA; ++h) {
            float M = -INFINITY;
#pragma unroll
            for (int i = 0; i < 8; ++i) M = fmaxf(M, lds_m[i][h]);
            float acc = 0.f, L = 0.f;
#pragma unroll
            for (int i = 0; i < 8; ++i) {
                const float w = __expf(lds_m[i][h] - M);
                L   += w * lds_l[i][h];
                acc += w * lds_o[i][h][d];
            }
            const int head = kvh * GQA + h;
            o_part[((size_t)head * SPLITS + split) * HEAD_DIM + d] = acc;
            if (d == 0) ml_part[head * SPLITS + split] = make_float2(M, L);
        }
    }
}

// ---------------- kernel 2: combine splits ----------------
__global__ __launch_bounds__(128) void attn_reduce(
    const float*  __restrict__ o_part,   // [32][SPLITS][128]
    const float2* __restrict__ ml_part,  // [32][SPLITS]
    float*        __restrict__ out)      // [32][128]
{
    const int h = blockIdx.x;
    const int d = threadIdx.x;

    __shared__ float2 mls[SPLITS];
    if (d < SPLITS) mls[d] = ml_part[h * SPLITS + d];
    __syncthreads();

    float M = -INFINITY;
#pragma unroll 8
    for (int s = 0; s < SPLITS; ++s) M = fmaxf(M, mls[s].x);

    float acc = 0.f, L = 0.f;
#pragma unroll 4
    for (int s = 0; s < SPLITS; ++s) {
        const float w = __expf(mls[s].x - M);
        L   += w * mls[s].y;
        acc += w * o_part[((size_t)h * SPLITS + s) * HEAD_DIM + d];
    }
    out[h * HEAD_DIM + d] = acc / L;
}

// ---------------- launcher ----------------
extern "C" void kernel_launch(void* const* d_in, const int* in_sizes, int n_in,
                              void* d_out, int out_size, void* d_ws, size_t ws_size,
                              hipStream_t stream) {
    const float* q    = (const float*)d_in[0];
    const float* knew = (const float*)d_in[1];
    const float* vnew = (const float*)d_in[2];
    const float* kc   = (const float*)d_in[3];
    const float* vc   = (const float*)d_in[4];
    const int*   bt   = (const int*)d_in[5];
    // d_in[6] slot_mapping, d_in[7] context_len, d_in[8] block_size: constants baked in.

    float*  o_part  = (float*)d_ws;
    float2* ml_part = (float2*)((char*)d_ws + (size_t)NUM_HEADS * SPLITS * HEAD_DIM * sizeof(float));

    attn_partial<<<dim3(SPLITS, NUM_KV_HEADS), 256, 0, stream>>>(
        q, knew, vnew, kc, vc, bt, o_part, ml_part);
    attn_reduce<<<NUM_HEADS, HEAD_DIM, 0, stream>>>(o_part, ml_part, (float*)d_out);
}